// Round 1
// baseline (66.835 us; speedup 1.0000x reference)
//
#include <hip/hip_runtime.h>
#include <math.h>

#define N_CELLS_C 100000
#define N_ISO_C 16
#define KP1_C 31
#define CELLS_PER_BLOCK 64
#define BLOCK 256

// Detect whether the index buffer is int64 (odd int32 words all zero) or int32.
__global__ void detect_idx_kernel(const int* __restrict__ idx32, int* __restrict__ flag) {
    if (threadIdx.x == 0) {
        int is64 = 1;
        for (int t = 0; t < 64; ++t) {
            if (idx32[2 * t + 1] != 0) { is64 = 0; break; }
        }
        *flag = is64;  // 1 => elements are 8 bytes, 0 => 4 bytes
    }
}

__global__ __launch_bounds__(BLOCK) void cost_kernel(
    const float* __restrict__ unsplice,
    const float* __restrict__ splices,
    const float* __restrict__ unsplice_predict,
    const float* __restrict__ splice_predicts,
    const char*  __restrict__ idx_bytes,
    const int*   __restrict__ flag,
    float*       __restrict__ partials)
{
    const int tid  = threadIdx.x;
    const int sub  = tid & 3;                       // which quarter of neighbors
    const int cell = blockIdx.x * CELLS_PER_BLOCK + (tid >> 2);
    const int shift = (*flag) ? 3 : 2;              // log2(bytes per index)

    float cost = 0.0f;
    if (cell < N_CELLS_C) {
        const float u_i  = unsplice[cell];
        const float up_i = unsplice_predict[cell];

        float s_i[N_ISO_C];
        float v[N_ISO_C];
        const float4* srow  = (const float4*)(splices         + (long long)cell * N_ISO_C);
        const float4* sprow = (const float4*)(splice_predicts + (long long)cell * N_ISO_C);

        const float uv = up_i - u_i;
        float vn2 = uv * uv;
        #pragma unroll
        for (int q = 0; q < 4; ++q) {
            float4 s4  = srow[q];
            float4 sp4 = sprow[q];
            float d0 = sp4.x - s4.x, d1 = sp4.y - s4.y, d2 = sp4.z - s4.z, d3 = sp4.w - s4.w;
            s_i[4*q+0] = s4.x; s_i[4*q+1] = s4.y; s_i[4*q+2] = s4.z; s_i[4*q+3] = s4.w;
            v[4*q+0] = d0; v[4*q+1] = d1; v[4*q+2] = d2; v[4*q+3] = d3;
            vn2 += d0*d0 + d1*d1 + d2*d2 + d3*d3;
        }
        const float vi_norm = sqrtf(vn2);

        float maxcos = -INFINITY;
        const long long base = (long long)cell * KP1_C;
        // neighbors k = 1..30, split across 4 lanes
        for (int k = 1 + sub; k < KP1_C; k += 4) {
            const int j = *(const int*)(idx_bytes + ((base + k) << shift));
            const float un  = unsplice[j] - u_i;
            float dot = uv * un;
            float nn2 = un * un;
            const float4* nrow = (const float4*)(splices + (long long)j * N_ISO_C);
            #pragma unroll
            for (int q = 0; q < 4; ++q) {
                float4 n4 = nrow[q];
                float d0 = n4.x - s_i[4*q+0];
                float d1 = n4.y - s_i[4*q+1];
                float d2 = n4.z - s_i[4*q+2];
                float d3 = n4.w - s_i[4*q+3];
                dot += v[4*q+0]*d0 + v[4*q+1]*d1 + v[4*q+2]*d2 + v[4*q+3]*d3;
                nn2 += d0*d0 + d1*d1 + d2*d2 + d3*d3;
            }
            float denom = vi_norm * sqrtf(nn2);
            if (denom == 0.0f) denom = 1.0f;
            maxcos = fmaxf(maxcos, dot / denom);
        }
        // max across the 4 lanes of this cell's group (xor 1,2 stays in group)
        maxcos = fmaxf(maxcos, __shfl_xor(maxcos, 1));
        maxcos = fmaxf(maxcos, __shfl_xor(maxcos, 2));
        if (sub == 0) cost = 1.0f - maxcos;
    }

    // block tree-sum (deterministic)
    for (int off = 32; off > 0; off >>= 1) cost += __shfl_down(cost, off);
    __shared__ float wsum[BLOCK / 64];
    const int wave = tid >> 6;
    const int lane = tid & 63;
    if (lane == 0) wsum[wave] = cost;
    __syncthreads();
    if (tid == 0) {
        float s = 0.0f;
        #pragma unroll
        for (int w = 0; w < BLOCK / 64; ++w) s += wsum[w];
        partials[blockIdx.x] = s;
    }
}

__global__ __launch_bounds__(BLOCK) void final_reduce_kernel(
    const float* __restrict__ partials, int nparts, float* __restrict__ out)
{
    float s = 0.0f;
    for (int i = threadIdx.x; i < nparts; i += BLOCK) s += partials[i];
    for (int off = 32; off > 0; off >>= 1) s += __shfl_down(s, off);
    __shared__ float wsum[BLOCK / 64];
    if ((threadIdx.x & 63) == 0) wsum[threadIdx.x >> 6] = s;
    __syncthreads();
    if (threadIdx.x == 0) {
        float t = 0.0f;
        #pragma unroll
        for (int w = 0; w < BLOCK / 64; ++w) t += wsum[w];
        out[0] = t / (float)N_CELLS_C;
    }
}

extern "C" void kernel_launch(void* const* d_in, const int* in_sizes, int n_in,
                              void* d_out, int out_size, void* d_ws, size_t ws_size,
                              hipStream_t stream) {
    const float* unsplice         = (const float*)d_in[0];
    const float* splices          = (const float*)d_in[1];
    const float* unsplice_predict = (const float*)d_in[2];
    const float* splice_predicts  = (const float*)d_in[3];
    const char*  idx_bytes        = (const char*)d_in[4];
    float* out = (float*)d_out;

    int*   flag     = (int*)d_ws;
    float* partials = (float*)((char*)d_ws + 256);

    const int nblocks = (N_CELLS_C + CELLS_PER_BLOCK - 1) / CELLS_PER_BLOCK;

    detect_idx_kernel<<<1, 64, 0, stream>>>((const int*)idx_bytes, flag);
    cost_kernel<<<nblocks, BLOCK, 0, stream>>>(
        unsplice, splices, unsplice_predict, splice_predicts,
        idx_bytes, flag, partials);
    final_reduce_kernel<<<1, BLOCK, 0, stream>>>(partials, nblocks, out);
}